// Round 1
// baseline (431.975 us; speedup 1.0000x reference)
//
#include <hip/hip_runtime.h>
#include <math.h>

#define S_LEN 2048
#define NH 16
#define DH 128
#define INNER 2048   // NH*DH
#define NROWS 4096   // B*S

typedef __attribute__((ext_vector_type(8))) short bf16x8;
typedef __attribute__((ext_vector_type(4))) float f32x4;

__device__ __forceinline__ short f2bf(float f) {
  union { float f; unsigned u; } v; v.f = f;
  unsigned r = (v.u + 0x7fffu + ((v.u >> 16) & 1u)) >> 16;
  return (short)(unsigned short)r;
}

// ---------------- prep kernels ----------------
__global__ void k_rope_table(float* __restrict__ rc, float* __restrict__ rs) {
  int idx = blockIdx.x * 256 + threadIdx.x;   // S_LEN * 64 entries
  int s = idx >> 6, i = idx & 63;
  double invf = pow(10000.0, -(double)i / 64.0);
  float ang = (float)((double)s * invf);
  float sv, cv;
  sincosf(ang, &sv, &cv);
  rc[idx] = cv; rs[idx] = sv;
}

__global__ void k_cvt_bf16(const float* __restrict__ in, short* __restrict__ out, int n) {
  int i = blockIdx.x * 256 + threadIdx.x;
  if (i < n) out[i] = f2bf(in[i]);
}

// transpose fp32 [R][C] -> bf16 [C][R]
__global__ void k_transpose_cvt(const float* __restrict__ in, short* __restrict__ out,
                                int R, int C) {
  __shared__ float tile[32][33];
  int c0 = blockIdx.x * 32, r0 = blockIdx.y * 32;
  int tx = threadIdx.x & 31, ty = threadIdx.x >> 5;   // 32 x 8
  #pragma unroll
  for (int dy = 0; dy < 32; dy += 8)
    tile[ty + dy][tx] = in[(size_t)(r0 + ty + dy) * C + c0 + tx];
  __syncthreads();
  #pragma unroll
  for (int dy = 0; dy < 32; dy += 8)
    out[(size_t)(c0 + ty + dy) * R + r0 + tx] = f2bf(tile[tx][ty + dy]);
}

// ---------------- QKV projection + RoPE ----------------
// grid (INNER/64=32, NROWS/128=32, 3), block 256
__global__ __launch_bounds__(256) void k_qkv(
    const short* __restrict__ Xbf, const short* __restrict__ WT,
    const float* __restrict__ rc, const float* __restrict__ rs,
    short* __restrict__ Qg, short* __restrict__ Kg, short* __restrict__ Vg) {
  __shared__ __attribute__((aligned(16))) short As[128 * 136];
  __shared__ __attribute__((aligned(16))) short Bs[64 * 136];
  const int tid = threadIdx.x;
  const int m0 = blockIdx.y * 128, n0 = blockIdx.x * 64, wz = blockIdx.z;
  const short* Wp = WT + (size_t)wz * INNER * 128;
  for (int c = tid; c < 128 * 16; c += 256) {
    int row = c >> 4, cj = c & 15;
    *(int4*)&As[row * 136 + cj * 8] = *(const int4*)&Xbf[(size_t)(m0 + row) * 128 + cj * 8];
  }
  for (int c = tid; c < 64 * 16; c += 256) {
    int row = c >> 4, cj = c & 15;
    *(int4*)&Bs[row * 136 + cj * 8] = *(const int4*)&Wp[(size_t)(n0 + row) * 128 + cj * 8];
  }
  __syncthreads();
  const int wid = tid >> 6, lane = tid & 63;
  const int l16 = lane & 15, quad = lane >> 4;
  const int wm = (wid & 1) * 64, wn = (wid >> 1) * 32;
  f32x4 acc[4][2] = {};
  #pragma unroll
  for (int ks = 0; ks < 4; ++ks) {
    bf16x8 a[4], b[2];
    #pragma unroll
    for (int mt = 0; mt < 4; ++mt)
      a[mt] = *(const bf16x8*)&As[(wm + mt * 16 + l16) * 136 + ks * 32 + quad * 8];
    #pragma unroll
    for (int nt = 0; nt < 2; ++nt)
      b[nt] = *(const bf16x8*)&Bs[(wn + nt * 16 + l16) * 136 + ks * 32 + quad * 8];
    #pragma unroll
    for (int mt = 0; mt < 4; ++mt)
      #pragma unroll
      for (int nt = 0; nt < 2; ++nt)
        acc[mt][nt] = __builtin_amdgcn_mfma_f32_16x16x32_bf16(a[mt], b[nt], acc[mt][nt], 0, 0, 0);
  }
  const float qscale = 0.08838834764831845f;  // 1/sqrt(128), folded into Q
  #pragma unroll
  for (int mt = 0; mt < 4; ++mt) {
    #pragma unroll
    for (int nt = 0; nt < 2; ++nt) {
      int gn = n0 + wn + nt * 16 + l16;
      int h = gn >> 7, d = gn & 127, i = d >> 1;
      #pragma unroll
      for (int r = 0; r < 4; ++r) {
        int gm = m0 + wm + mt * 16 + quad * 4 + r;
        int bb = gm >> 11, s = gm & 2047;
        float v = acc[mt][nt][r];
        float res;
        if (wz < 2) {
          float pv = __shfl_xor(v, 1);            // partner holds d^1 (col=lane&15)
          float cv = rc[s * 64 + i], sv = rs[s * 64 + i];
          res = (d & 1) ? (v * cv + pv * sv) : (v * cv - pv * sv);
          if (wz == 0) res *= qscale;
        } else res = v;
        size_t off = (((size_t)(bb * NH + h)) * S_LEN + s) * DH + d;
        short bv = f2bf(res);
        if (wz == 0) Qg[off] = bv; else if (wz == 1) Kg[off] = bv; else Vg[off] = bv;
      }
    }
  }
}

// ---------------- V transpose: [bh][s][d] -> [bh][d][s] ----------------
__global__ __launch_bounds__(256) void k_vt(const short* __restrict__ Vg,
                                            short* __restrict__ VTg) {
  __shared__ short t[64][65];
  int s0 = blockIdx.x * 64, d0 = blockIdx.y * 64, bh = blockIdx.z;
  const short* src = Vg + (size_t)bh * S_LEN * DH;
  short* dst = VTg + (size_t)bh * S_LEN * DH;
  int tid = threadIdx.x;
  for (int e = tid; e < 4096; e += 256) {
    int r = e >> 6, c = e & 63;           // r: s_local, c: d_local
    t[r][c] = src[(size_t)(s0 + r) * DH + d0 + c];
  }
  __syncthreads();
  for (int e = tid; e < 4096; e += 256) {
    int r = e >> 6, c = e & 63;           // r: d_local, c: s_local
    dst[(size_t)(d0 + r) * S_LEN + s0 + c] = t[c][r];
  }
}

// ---------------- flash attention ----------------
// grid (S/64=32 qt, B*H=32), block 256 (4 waves, 16 q-rows each)
__global__ __launch_bounds__(256) void k_attn(
    const short* __restrict__ Qg, const short* __restrict__ Kg,
    const short* __restrict__ VTg, short* __restrict__ Og) {
  __shared__ __attribute__((aligned(16))) short Qs[64 * 136];
  __shared__ __attribute__((aligned(16))) short Ks[64 * 136];
  __shared__ __attribute__((aligned(16))) short Vs[128 * 72];  // V^T: [d][t]
  __shared__ __attribute__((aligned(16))) short Ps[64 * 72];
  const int qt = blockIdx.x, bh = blockIdx.y;
  const int bb = bh >> 4, h = bh & 15;
  const int tid = threadIdx.x, wid = tid >> 6, lane = tid & 63;
  const int l16 = lane & 15, quad = lane >> 4;
  const int q0 = qt * 64, wq = wid * 16;
  const short* Qp = Qg + ((size_t)bh * S_LEN + q0) * DH;
  const short* Kp = Kg + (size_t)bh * S_LEN * DH;
  const short* Vp = VTg + (size_t)bh * S_LEN * DH;
  for (int c = tid; c < 64 * 16; c += 256) {
    int row = c >> 4, cj = c & 15;
    *(int4*)&Qs[row * 136 + cj * 8] = *(const int4*)&Qp[(size_t)row * 128 + cj * 8];
  }
  float m_i[4], l_i[4];
  f32x4 Oacc[8] = {};
  #pragma unroll
  for (int r = 0; r < 4; ++r) { m_i[r] = -1e30f; l_i[r] = 0.0f; }
  __syncthreads();
  for (int j = 0; j <= qt; ++j) {
    for (int c = tid; c < 64 * 16; c += 256) {
      int row = c >> 4, cj = c & 15;
      *(int4*)&Ks[row * 136 + cj * 8] =
          *(const int4*)&Kp[(size_t)(j * 64 + row) * 128 + cj * 8];
    }
    for (int c = tid; c < 128 * 8; c += 256) {
      int row = c >> 3, cj = c & 7;
      *(int4*)&Vs[row * 72 + cj * 8] =
          *(const int4*)&Vp[(size_t)row * S_LEN + j * 64 + cj * 8];
    }
    __syncthreads();
    f32x4 Sc[4] = {};
    #pragma unroll
    for (int ks = 0; ks < 4; ++ks) {
      bf16x8 a = *(const bf16x8*)&Qs[(wq + l16) * 136 + ks * 32 + quad * 8];
      #pragma unroll
      for (int nt = 0; nt < 4; ++nt) {
        bf16x8 b = *(const bf16x8*)&Ks[(nt * 16 + l16) * 136 + ks * 32 + quad * 8];
        Sc[nt] = __builtin_amdgcn_mfma_f32_16x16x32_bf16(a, b, Sc[nt], 0, 0, 0);
      }
    }
    if (j == qt) {   // diagonal tile: causal mask
      #pragma unroll
      for (int nt = 0; nt < 4; ++nt)
        #pragma unroll
        for (int r = 0; r < 4; ++r) {
          int srow = wq + quad * 4 + r, tcol = nt * 16 + l16;
          if (tcol > srow) Sc[nt][r] = -1e30f;
        }
    }
    #pragma unroll
    for (int r = 0; r < 4; ++r) {
      float mx = fmaxf(fmaxf(Sc[0][r], Sc[1][r]), fmaxf(Sc[2][r], Sc[3][r]));
      #pragma unroll
      for (int msk = 1; msk < 16; msk <<= 1) mx = fmaxf(mx, __shfl_xor(mx, msk));
      float mnew = fmaxf(m_i[r], mx);
      float alpha = __expf(m_i[r] - mnew);
      m_i[r] = mnew;
      float rsum = 0.0f;
      #pragma unroll
      for (int nt = 0; nt < 4; ++nt) {
        float p = __expf(Sc[nt][r] - mnew);
        Sc[nt][r] = p;
        rsum += p;
      }
      #pragma unroll
      for (int msk = 1; msk < 16; msk <<= 1) rsum += __shfl_xor(rsum, msk);
      l_i[r] = l_i[r] * alpha + rsum;
      #pragma unroll
      for (int nt = 0; nt < 8; ++nt) Oacc[nt][r] *= alpha;
    }
    // P: C-layout -> A-layout via LDS (wave-private rows; in-order DS pipe)
    #pragma unroll
    for (int nt = 0; nt < 4; ++nt)
      #pragma unroll
      for (int r = 0; r < 4; ++r)
        Ps[(wq + quad * 4 + r) * 72 + nt * 16 + l16] = f2bf(Sc[nt][r]);
    #pragma unroll
    for (int ks = 0; ks < 2; ++ks) {
      bf16x8 a = *(const bf16x8*)&Ps[(wq + l16) * 72 + ks * 32 + quad * 8];
      #pragma unroll
      for (int nt = 0; nt < 8; ++nt) {
        bf16x8 b = *(const bf16x8*)&Vs[(nt * 16 + l16) * 72 + ks * 32 + quad * 8];
        Oacc[nt] = __builtin_amdgcn_mfma_f32_16x16x32_bf16(a, b, Oacc[nt], 0, 0, 0);
      }
    }
    __syncthreads();
  }
  #pragma unroll
  for (int nt = 0; nt < 8; ++nt)
    #pragma unroll
    for (int r = 0; r < 4; ++r) {
      int srow = wq + quad * 4 + r, d = nt * 16 + l16;
      float v = Oacc[nt][r] / l_i[r];
      Og[((size_t)(bb * S_LEN + q0 + srow)) * INNER + h * DH + d] = f2bf(v);
    }
}

// ---------------- output projection: Og[4096,2048] @ Wo[2048,128] ----------------
// grid (NROWS/128=32, splitK=4), block 256; atomicAdd into zeroed d_out
__global__ __launch_bounds__(256) void k_out(
    const short* __restrict__ Og, const short* __restrict__ WoT,
    float* __restrict__ out) {
  __shared__ __attribute__((aligned(16))) short As[128 * 72];
  __shared__ __attribute__((aligned(16))) short Bs[128 * 72];
  const int m0 = blockIdx.x * 128, kb0 = blockIdx.y * 512;
  const int tid = threadIdx.x, wid = tid >> 6, lane = tid & 63;
  const int l16 = lane & 15, quad = lane >> 4;
  const int wm = (wid & 1) * 64, wn = (wid >> 1) * 64;
  f32x4 acc[4][4] = {};
  for (int kc = 0; kc < 8; ++kc) {
    int k0 = kb0 + kc * 64;
    for (int c = tid; c < 128 * 8; c += 256) {
      int row = c >> 3, cj = c & 7;
      *(int4*)&As[row * 72 + cj * 8] =
          *(const int4*)&Og[(size_t)(m0 + row) * INNER + k0 + cj * 8];
    }
    for (int c = tid; c < 128 * 8; c += 256) {
      int row = c >> 3, cj = c & 7;
      *(int4*)&Bs[row * 72 + cj * 8] =
          *(const int4*)&WoT[(size_t)row * INNER + k0 + cj * 8];
    }
    __syncthreads();
    #pragma unroll
    for (int ks = 0; ks < 2; ++ks) {
      bf16x8 a[4], b[4];
      #pragma unroll
      for (int mt = 0; mt < 4; ++mt)
        a[mt] = *(const bf16x8*)&As[(wm + mt * 16 + l16) * 72 + ks * 32 + quad * 8];
      #pragma unroll
      for (int nt = 0; nt < 4; ++nt)
        b[nt] = *(const bf16x8*)&Bs[(wn + nt * 16 + l16) * 72 + ks * 32 + quad * 8];
      #pragma unroll
      for (int mt = 0; mt < 4; ++mt)
        #pragma unroll
        for (int nt = 0; nt < 4; ++nt)
          acc[mt][nt] = __builtin_amdgcn_mfma_f32_16x16x32_bf16(a[mt], b[nt], acc[mt][nt], 0, 0, 0);
    }
    __syncthreads();
  }
  #pragma unroll
  for (int mt = 0; mt < 4; ++mt)
    #pragma unroll
    for (int nt = 0; nt < 4; ++nt)
      #pragma unroll
      for (int r = 0; r < 4; ++r) {
        int gm = m0 + wm + mt * 16 + quad * 4 + r;
        int gn = wn + nt * 16 + l16;
        atomicAdd(&out[(size_t)gm * 128 + gn], acc[mt][nt][r]);
      }
}

// ---------------- launch ----------------
extern "C" void kernel_launch(void* const* d_in, const int* in_sizes, int n_in,
                              void* d_out, int out_size, void* d_ws, size_t ws_size,
                              hipStream_t stream) {
  const float* q  = (const float*)d_in[0];
  const float* Wq = (const float*)d_in[1];
  const float* Wk = (const float*)d_in[2];
  const float* Wv = (const float*)d_in[3];
  const float* Wo = (const float*)d_in[4];
  float* out = (float*)d_out;
  char* ws = (char*)d_ws;
  const size_t MB = 1024 * 1024;
  // ws layout (needs 84 MB total)
  float* rc  = (float*)(ws + 0);                 // 512 KB
  float* rs  = (float*)(ws + 512 * 1024);        // 512 KB
  short* Xbf = (short*)(ws + 1 * MB);            // 1 MB
  short* WT  = (short*)(ws + 2 * MB);            // 1.5 MB (Wq,Wk,Wv transposed bf16)
  short* WoT = (short*)(ws + 3 * MB + 512 * 1024); // 512 KB
  short* Qg  = (short*)(ws + 4 * MB);            // 16 MB  [bh][s][d]
  short* Kg  = (short*)(ws + 20 * MB);           // 16 MB
  short* Vg  = (short*)(ws + 36 * MB);           // 16 MB
  short* VTg = (short*)(ws + 52 * MB);           // 16 MB  [bh][d][s]
  short* Og  = (short*)(ws + 68 * MB);           // 16 MB  [b*s][h*d]

  k_rope_table<<<512, 256, 0, stream>>>(rc, rs);
  k_cvt_bf16<<<2048, 256, 0, stream>>>(q, Xbf, NROWS * 128);
  k_transpose_cvt<<<dim3(64, 4), 256, 0, stream>>>(Wq, WT, 128, INNER);
  k_transpose_cvt<<<dim3(64, 4), 256, 0, stream>>>(Wk, WT + (size_t)INNER * 128, 128, INNER);
  k_transpose_cvt<<<dim3(64, 4), 256, 0, stream>>>(Wv, WT + 2 * (size_t)INNER * 128, 128, INNER);
  k_transpose_cvt<<<dim3(4, 64), 256, 0, stream>>>(Wo, WoT, INNER, 128);
  k_qkv<<<dim3(32, 32, 3), 256, 0, stream>>>(Xbf, WT, rc, rs, Qg, Kg, Vg);
  k_vt<<<dim3(32, 2, 32), 256, 0, stream>>>(Vg, VTg);
  k_attn<<<dim3(32, 32), 256, 0, stream>>>(Qg, Kg, VTg, Og);
  hipMemsetAsync(d_out, 0, (size_t)out_size * sizeof(float), stream);
  k_out<<<dim3(32, 4), 256, 0, stream>>>(Og, WoT, out);
}

// Round 2
// 282.185 us; speedup vs baseline: 1.5308x; 1.5308x over previous
//
#include <hip/hip_runtime.h>
#include <math.h>

#define S_LEN 2048
#define NH 16
#define DH 128
#define INNER 2048   // NH*DH
#define NROWS 4096   // B*S

typedef __attribute__((ext_vector_type(8))) short bf16x8;
typedef __attribute__((ext_vector_type(4))) float f32x4;

__device__ __forceinline__ short f2bf(float f) {
  union { float f; unsigned u; } v; v.f = f;
  unsigned r = (v.u + 0x7fffu + ((v.u >> 16) & 1u)) >> 16;
  return (short)(unsigned short)r;
}

// ---------------- prep kernels ----------------
__global__ void k_rope_table(float* __restrict__ rc, float* __restrict__ rs) {
  int idx = blockIdx.x * 256 + threadIdx.x;   // S_LEN * 64 entries
  int s = idx >> 6, i = idx & 63;
  double invf = pow(10000.0, -(double)i / 64.0);
  float ang = (float)((double)s * invf);
  float sv, cv;
  sincosf(ang, &sv, &cv);
  rc[idx] = cv; rs[idx] = sv;
}

__global__ void k_cvt_bf16(const float* __restrict__ in, short* __restrict__ out, int n) {
  int i = blockIdx.x * 256 + threadIdx.x;
  if (i < n) out[i] = f2bf(in[i]);
}

// transpose fp32 [R][C] -> bf16 [C][R]
__global__ void k_transpose_cvt(const float* __restrict__ in, short* __restrict__ out,
                                int R, int C) {
  __shared__ float tile[32][33];
  int c0 = blockIdx.x * 32, r0 = blockIdx.y * 32;
  int tx = threadIdx.x & 31, ty = threadIdx.x >> 5;   // 32 x 8
  #pragma unroll
  for (int dy = 0; dy < 32; dy += 8)
    tile[ty + dy][tx] = in[(size_t)(r0 + ty + dy) * C + c0 + tx];
  __syncthreads();
  #pragma unroll
  for (int dy = 0; dy < 32; dy += 8)
    out[(size_t)(c0 + ty + dy) * R + r0 + tx] = f2bf(tile[tx][ty + dy]);
}

// ---------------- QKV projection + RoPE ----------------
// grid (INNER/64=32, NROWS/128=32, 3), block 256
// Q,K written [bh][s][d]; V written TRANSPOSED [bh][d][s]
__global__ __launch_bounds__(256) void k_qkv(
    const short* __restrict__ Xbf, const short* __restrict__ WT,
    const float* __restrict__ rc, const float* __restrict__ rs,
    short* __restrict__ Qg, short* __restrict__ Kg, short* __restrict__ Vg) {
  __shared__ __attribute__((aligned(16))) short As[128 * 136];
  __shared__ __attribute__((aligned(16))) short Bs[64 * 136];
  const int tid = threadIdx.x;
  const int m0 = blockIdx.y * 128, n0 = blockIdx.x * 64, wz = blockIdx.z;
  const short* Wp = WT + (size_t)wz * INNER * 128;
  for (int c = tid; c < 128 * 16; c += 256) {
    int row = c >> 4, cj = c & 15;
    *(int4*)&As[row * 136 + cj * 8] = *(const int4*)&Xbf[(size_t)(m0 + row) * 128 + cj * 8];
  }
  for (int c = tid; c < 64 * 16; c += 256) {
    int row = c >> 4, cj = c & 15;
    *(int4*)&Bs[row * 136 + cj * 8] = *(const int4*)&Wp[(size_t)(n0 + row) * 128 + cj * 8];
  }
  __syncthreads();
  const int wid = tid >> 6, lane = tid & 63;
  const int l16 = lane & 15, quad = lane >> 4;
  const int wm = (wid & 1) * 64, wn = (wid >> 1) * 32;
  f32x4 acc[4][2] = {};
  #pragma unroll
  for (int ks = 0; ks < 4; ++ks) {
    bf16x8 a[4], b[2];
    #pragma unroll
    for (int mt = 0; mt < 4; ++mt)
      a[mt] = *(const bf16x8*)&As[(wm + mt * 16 + l16) * 136 + ks * 32 + quad * 8];
    #pragma unroll
    for (int nt = 0; nt < 2; ++nt)
      b[nt] = *(const bf16x8*)&Bs[(wn + nt * 16 + l16) * 136 + ks * 32 + quad * 8];
    #pragma unroll
    for (int mt = 0; mt < 4; ++mt)
      #pragma unroll
      for (int nt = 0; nt < 2; ++nt)
        acc[mt][nt] = __builtin_amdgcn_mfma_f32_16x16x32_bf16(a[mt], b[nt], acc[mt][nt], 0, 0, 0);
  }
  const float qscale = 0.08838834764831845f;  // 1/sqrt(128), folded into Q
  if (wz < 2) {
    #pragma unroll
    for (int mt = 0; mt < 4; ++mt)
      #pragma unroll
      for (int nt = 0; nt < 2; ++nt) {
        int gn = n0 + wn + nt * 16 + l16;
        int h = gn >> 7, d = gn & 127, i = d >> 1;
        #pragma unroll
        for (int r = 0; r < 4; ++r) {
          int gm = m0 + wm + mt * 16 + quad * 4 + r;
          int bb = gm >> 11, s = gm & 2047;
          float v = acc[mt][nt][r];
          float pv = __shfl_xor(v, 1);            // partner holds d^1 (col=lane&15)
          float cv = rc[s * 64 + i], sv = rs[s * 64 + i];
          float res = (d & 1) ? (v * cv + pv * sv) : (v * cv - pv * sv);
          if (wz == 0) res *= qscale;
          size_t off = (((size_t)(bb * NH + h)) * S_LEN + s) * DH + d;
          short bv = f2bf(res);
          if (wz == 0) Qg[off] = bv; else Kg[off] = bv;
        }
      }
  } else {
    // V: packed transposed store [bh][d][s], 4 consecutive s per short4
    #pragma unroll
    for (int mt = 0; mt < 4; ++mt)
      #pragma unroll
      for (int nt = 0; nt < 2; ++nt) {
        int gn = n0 + wn + nt * 16 + l16;
        int h = gn >> 7, d = gn & 127;
        int gmb = m0 + wm + mt * 16 + quad * 4;
        int bb = gmb >> 11, s = gmb & 2047;
        short4 pk;
        pk.x = f2bf(acc[mt][nt][0]); pk.y = f2bf(acc[mt][nt][1]);
        pk.z = f2bf(acc[mt][nt][2]); pk.w = f2bf(acc[mt][nt][3]);
        *(short4*)&Vg[(((size_t)(bb * NH + h)) * DH + d) * S_LEN + s] = pk;
      }
  }
}

// ---------------- flash attention, S^T formulation ----------------
// grid (16 pair, B*H=32), block 256 (4 waves). Block handles Q-tiles
// qt = x and 31-x (work (x+1)+(32-x)=33, perfectly balanced, 2 blocks/CU).
// S^T = K @ Q^T: C-layout puts softmax axis (t) in-lane -> 2 shfls/reduction,
// and P^T regs are 4 consecutive t -> packed b64 LDS stores.
__global__ __launch_bounds__(256, 2) void k_attn(
    const short* __restrict__ Qg, const short* __restrict__ Kg,
    const short* __restrict__ Vg, short* __restrict__ Og) {
  __shared__ __attribute__((aligned(16))) short Qs[64 * 136];  // [q][d]
  __shared__ __attribute__((aligned(16))) short Ks[64 * 136];  // [t][d]
  __shared__ __attribute__((aligned(16))) short Vs[128 * 72];  // [d][t]
  __shared__ __attribute__((aligned(16))) short Ps[64 * 72];   // [q][t]
  const int bh = blockIdx.y, bb = bh >> 4, h = bh & 15;
  const int tid = threadIdx.x, wid = tid >> 6, lane = tid & 63;
  const int l16 = lane & 15, quad = lane >> 4, wq = wid * 16;
  const short* Kp = Kg + (size_t)bh * S_LEN * DH;
  const short* Vp = Vg + (size_t)bh * S_LEN * DH;  // [d][s]

  for (int ph = 0; ph < 2; ++ph) {
    const int qt = ph ? (31 - (int)blockIdx.x) : (int)blockIdx.x;
    const int q0 = qt * 64;
    // stage Q tile (visibility covered by first loop-top barrier)
    const short* Qp = Qg + ((size_t)bh * S_LEN + q0) * DH;
    for (int e = tid; e < 1024; e += 256) {
      int row = e >> 4, cj = e & 15;
      *(int4*)&Qs[row * 136 + cj * 8] = *(const int4*)&Qp[(size_t)row * 128 + cj * 8];
    }
    float m_i = -1e30f, l_i = 0.0f;
    f32x4 Oacc[8] = {};
    // prefetch KV tile 0 into registers
    int4 kr[4], vr[4];
    #pragma unroll
    for (int i = 0; i < 4; ++i) {
      int e = tid + 256 * i;
      kr[i] = *(const int4*)&Kp[(size_t)(e >> 4) * 128 + (e & 15) * 8];
      vr[i] = *(const int4*)&Vp[(size_t)(e >> 3) * S_LEN + (e & 7) * 8];
    }
    for (int j = 0; j <= qt; ++j) {
      // store prefetched K/V to LDS
      #pragma unroll
      for (int i = 0; i < 4; ++i) {
        int e = tid + 256 * i;
        *(int4*)&Ks[(e >> 4) * 136 + (e & 15) * 8] = kr[i];
        *(int4*)&Vs[(e >> 3) * 72 + (e & 7) * 8] = vr[i];
      }
      __syncthreads();
      if (j < qt) {  // prefetch next tile; latency hides behind compute
        #pragma unroll
        for (int i = 0; i < 4; ++i) {
          int e = tid + 256 * i;
          kr[i] = *(const int4*)&Kp[(size_t)((j + 1) * 64 + (e >> 4)) * 128 + (e & 15) * 8];
          vr[i] = *(const int4*)&Vp[(size_t)(e >> 3) * S_LEN + (j + 1) * 64 + (e & 7) * 8];
        }
      }
      // S^T tile: D[t][q], A=K (m=t), B=Q (n=q); wave covers t=64 x q=16
      f32x4 Sc[4] = {};
      #pragma unroll
      for (int ks = 0; ks < 4; ++ks) {
        bf16x8 bq = *(const bf16x8*)&Qs[(wq + l16) * 136 + ks * 32 + quad * 8];
        #pragma unroll
        for (int nt = 0; nt < 4; ++nt) {
          bf16x8 ak = *(const bf16x8*)&Ks[(nt * 16 + l16) * 136 + ks * 32 + quad * 8];
          Sc[nt] = __builtin_amdgcn_mfma_f32_16x16x32_bf16(ak, bq, Sc[nt], 0, 0, 0);
        }
      }
      if (j == qt) {  // causal mask on diagonal tile: t_local > q_local
        #pragma unroll
        for (int nt = 0; nt < 4; ++nt)
          #pragma unroll
          for (int r = 0; r < 4; ++r)
            if (nt * 16 + quad * 4 + r > wq + l16) Sc[nt][r] = -1e30f;
      }
      // online softmax over t (in-lane 16 values + 2 cross-quad shfls)
      float mloc = -1e30f;
      #pragma unroll
      for (int nt = 0; nt < 4; ++nt)
        #pragma unroll
        for (int r = 0; r < 4; ++r) mloc = fmaxf(mloc, Sc[nt][r]);
      mloc = fmaxf(mloc, __shfl_xor(mloc, 16));
      mloc = fmaxf(mloc, __shfl_xor(mloc, 32));
      float mnew = fmaxf(m_i, mloc);
      float alpha = __expf(m_i - mnew);
      m_i = mnew;
      float rsum = 0.0f;
      #pragma unroll
      for (int nt = 0; nt < 4; ++nt)
        #pragma unroll
        for (int r = 0; r < 4; ++r) {
          float p = __expf(Sc[nt][r] - mnew);
          Sc[nt][r] = p;
          rsum += p;
        }
      rsum += __shfl_xor(rsum, 16);
      rsum += __shfl_xor(rsum, 32);
      l_i = l_i * alpha + rsum;
      #pragma unroll
      for (int nt = 0; nt < 8; ++nt)
        #pragma unroll
        for (int r = 0; r < 4; ++r) Oacc[nt][r] *= alpha;
      // P^T -> Ps[q][t]: 4 consecutive t per reg quad -> packed b64 stores
      #pragma unroll
      for (int nt = 0; nt < 4; ++nt) {
        short4 pk;
        pk.x = f2bf(Sc[nt][0]); pk.y = f2bf(Sc[nt][1]);
        pk.z = f2bf(Sc[nt][2]); pk.w = f2bf(Sc[nt][3]);
        *(short4*)&Ps[(wq + l16) * 72 + nt * 16 + quad * 4] = pk;
      }
      // O^T += V^T @ P : A=V (m=d), B=P (n=q); wave-private q rows of Ps
      #pragma unroll
      for (int ks = 0; ks < 2; ++ks) {
        bf16x8 bp = *(const bf16x8*)&Ps[(wq + l16) * 72 + ks * 32 + quad * 8];
        #pragma unroll
        for (int nt = 0; nt < 8; ++nt) {
          bf16x8 av = *(const bf16x8*)&Vs[(nt * 16 + l16) * 72 + ks * 32 + quad * 8];
          Oacc[nt] = __builtin_amdgcn_mfma_f32_16x16x32_bf16(av, bp, Oacc[nt], 0, 0, 0);
        }
      }
      __syncthreads();
    }
    // write O: Oacc[nt][r] = O[q = q0+wq+l16][d = nt*16+quad*4+r] / l_i
    float inv = 1.0f / l_i;
    size_t orow = ((size_t)(bb * S_LEN + q0 + wq + l16)) * INNER + h * DH;
    #pragma unroll
    for (int nt = 0; nt < 8; ++nt) {
      short4 ov;
      ov.x = f2bf(Oacc[nt][0] * inv); ov.y = f2bf(Oacc[nt][1] * inv);
      ov.z = f2bf(Oacc[nt][2] * inv); ov.w = f2bf(Oacc[nt][3] * inv);
      *(short4*)&Og[orow + nt * 16 + quad * 4] = ov;
    }
  }
}

// ---------------- output projection: Og[4096,2048] @ Wo[2048,128] ----------------
// grid (NROWS/128=32, splitK=4), block 256; atomicAdd into zeroed d_out
__global__ __launch_bounds__(256) void k_out(
    const short* __restrict__ Og, const short* __restrict__ WoT,
    float* __restrict__ out) {
  __shared__ __attribute__((aligned(16))) short As[128 * 72];
  __shared__ __attribute__((aligned(16))) short Bs[128 * 72];
  const int m0 = blockIdx.x * 128, kb0 = blockIdx.y * 512;
  const int tid = threadIdx.x, wid = tid >> 6, lane = tid & 63;
  const int l16 = lane & 15, quad = lane >> 4;
  const int wm = (wid & 1) * 64, wn = (wid >> 1) * 64;
  f32x4 acc[4][4] = {};
  for (int kc = 0; kc < 8; ++kc) {
    int k0 = kb0 + kc * 64;
    for (int c = tid; c < 128 * 8; c += 256) {
      int row = c >> 3, cj = c & 7;
      *(int4*)&As[row * 72 + cj * 8] =
          *(const int4*)&Og[(size_t)(m0 + row) * INNER + k0 + cj * 8];
    }
    for (int c = tid; c < 128 * 8; c += 256) {
      int row = c >> 3, cj = c & 7;
      *(int4*)&Bs[row * 72 + cj * 8] =
          *(const int4*)&WoT[(size_t)row * INNER + k0 + cj * 8];
    }
    __syncthreads();
    #pragma unroll
    for (int ks = 0; ks < 2; ++ks) {
      bf16x8 a[4], b[4];
      #pragma unroll
      for (int mt = 0; mt < 4; ++mt)
        a[mt] = *(const bf16x8*)&As[(wm + mt * 16 + l16) * 72 + ks * 32 + quad * 8];
      #pragma unroll
      for (int nt = 0; nt < 4; ++nt)
        b[nt] = *(const bf16x8*)&Bs[(wn + nt * 16 + l16) * 72 + ks * 32 + quad * 8];
      #pragma unroll
      for (int mt = 0; mt < 4; ++mt)
        #pragma unroll
        for (int nt = 0; nt < 4; ++nt)
          acc[mt][nt] = __builtin_amdgcn_mfma_f32_16x16x32_bf16(a[mt], b[nt], acc[mt][nt], 0, 0, 0);
    }
    __syncthreads();
  }
  #pragma unroll
  for (int mt = 0; mt < 4; ++mt)
    #pragma unroll
    for (int nt = 0; nt < 4; ++nt)
      #pragma unroll
      for (int r = 0; r < 4; ++r) {
        int gm = m0 + wm + mt * 16 + quad * 4 + r;
        int gn = wn + nt * 16 + l16;
        atomicAdd(&out[(size_t)gm * 128 + gn], acc[mt][nt][r]);
      }
}

// ---------------- launch ----------------
extern "C" void kernel_launch(void* const* d_in, const int* in_sizes, int n_in,
                              void* d_out, int out_size, void* d_ws, size_t ws_size,
                              hipStream_t stream) {
  const float* q  = (const float*)d_in[0];
  const float* Wq = (const float*)d_in[1];
  const float* Wk = (const float*)d_in[2];
  const float* Wv = (const float*)d_in[3];
  const float* Wo = (const float*)d_in[4];
  float* out = (float*)d_out;
  char* ws = (char*)d_ws;
  const size_t MB = 1024 * 1024;
  float* rc  = (float*)(ws + 0);                 // 512 KB
  float* rs  = (float*)(ws + 512 * 1024);        // 512 KB
  short* Xbf = (short*)(ws + 1 * MB);            // 1 MB
  short* WT  = (short*)(ws + 2 * MB);            // 1.5 MB (Wq,Wk,Wv transposed bf16)
  short* WoT = (short*)(ws + 3 * MB + 512 * 1024); // 512 KB
  short* Qg  = (short*)(ws + 4 * MB);            // 16 MB  [bh][s][d]
  short* Kg  = (short*)(ws + 20 * MB);           // 16 MB  [bh][s][d]
  short* Vg  = (short*)(ws + 36 * MB);           // 16 MB  [bh][d][s]  (written transposed)
  short* Og  = (short*)(ws + 68 * MB);           // 16 MB  [b*s][h*d]

  k_rope_table<<<512, 256, 0, stream>>>(rc, rs);
  k_cvt_bf16<<<2048, 256, 0, stream>>>(q, Xbf, NROWS * 128);
  k_transpose_cvt<<<dim3(64, 4), 256, 0, stream>>>(Wq, WT, 128, INNER);
  k_transpose_cvt<<<dim3(64, 4), 256, 0, stream>>>(Wk, WT + (size_t)INNER * 128, 128, INNER);
  k_transpose_cvt<<<dim3(64, 4), 256, 0, stream>>>(Wv, WT + 2 * (size_t)INNER * 128, 128, INNER);
  k_transpose_cvt<<<dim3(4, 64), 256, 0, stream>>>(Wo, WoT, INNER, 128);
  k_qkv<<<dim3(32, 32, 3), 256, 0, stream>>>(Xbf, WT, rc, rs, Qg, Kg, Vg);
  k_attn<<<dim3(16, 32), 256, 0, stream>>>(Qg, Kg, Vg, Og);
  hipMemsetAsync(d_out, 0, (size_t)out_size * sizeof(float), stream);
  k_out<<<dim3(32, 4), 256, 0, stream>>>(Og, WoT, out);
}